// Round 16
// baseline (376.694 us; speedup 1.0000x reference)
//
#include <hip/hip_runtime.h>
#include <hip/hip_bf16.h>
#include <math.h>

#define DMODEL 1024
#define NH     16
#define HD     64
#define FFDIM  4096
#define SEQ    1024
#define BATCH  8
#define ROWS   (BATCH * SEQ)  // 8192

typedef __bf16 bf16x8 __attribute__((ext_vector_type(8)));
typedef __bf16 bf16x4 __attribute__((ext_vector_type(4)));
typedef float  f32x4  __attribute__((ext_vector_type(4)));
typedef short  s16x4  __attribute__((ext_vector_type(4)));
typedef unsigned int u32x2 __attribute__((ext_vector_type(2)));

__device__ __forceinline__ unsigned short f2bf(float f) {
  unsigned int u = __builtin_bit_cast(unsigned int, f);
  u += 0x7fff + ((u >> 16) & 1);
  return (unsigned short)(u >> 16);
}

__device__ __forceinline__ unsigned int cvt_pk_bf16(float lo, float hi) {
  unsigned int r;
  asm("v_cvt_pk_bf16_f32 %0, %1, %2" : "=v"(r) : "v"(lo), "v"(hi));
  return r;
}

__device__ __forceinline__ void gload_lds16(const void* g, void* l) {
  __builtin_amdgcn_global_load_lds(
      (const __attribute__((address_space(1))) unsigned int*)g,
      (__attribute__((address_space(3))) unsigned int*)l, 16, 0, 0);
}

// ---------------- LayerNorm: f32 [rows][1024] -> bf16 ----------------
__global__ __launch_bounds__(256) void ln_bf16_kernel(
    const float* __restrict__ x, const float* __restrict__ g,
    const float* __restrict__ bta, unsigned short* __restrict__ out) {
  int row = blockIdx.x;
  int tid = threadIdx.x;
  int wid = tid >> 6, lane = tid & 63;
  const float4 v = ((const float4*)(x + (size_t)row * DMODEL))[tid];
  float s = v.x + v.y + v.z + v.w;
#pragma unroll
  for (int off = 32; off >= 1; off >>= 1) s += __shfl_xor(s, off, 64);
  __shared__ float red[8];
  if (lane == 0) red[wid] = s;
  __syncthreads();
  float mu = (red[0] + red[1] + red[2] + red[3]) * (1.0f / DMODEL);
  float4 d;
  d.x = v.x - mu; d.y = v.y - mu; d.z = v.z - mu; d.w = v.w - mu;
  float sq = d.x * d.x + d.y * d.y + d.z * d.z + d.w * d.w;
#pragma unroll
  for (int off = 32; off >= 1; off >>= 1) sq += __shfl_xor(sq, off, 64);
  if (lane == 0) red[4 + wid] = sq;
  __syncthreads();
  float var = (red[4] + red[5] + red[6] + red[7]) * (1.0f / DMODEL);
  float rs = rsqrtf(var + 1e-5f);
  const float4 gg = ((const float4*)g)[tid];
  const float4 bb = ((const float4*)bta)[tid];
  ushort4 o;
  o.x = f2bf(d.x * rs * gg.x + bb.x);
  o.y = f2bf(d.y * rs * gg.y + bb.y);
  o.z = f2bf(d.z * rs * gg.z + bb.z);
  o.w = f2bf(d.w * rs * gg.w + bb.w);
  ((ushort4*)(out + (size_t)row * DMODEL))[tid] = o;
}

// ------------- transpose f32 [R][C] -> bf16 [C][R], batched -------------
__global__ __launch_bounds__(256) void transpose_f2b_kernel(
    const float* __restrict__ in, unsigned short* __restrict__ out,
    int R, int C, long long ibs, long long obs) {
  __shared__ float tile[64][65];
  int b = blockIdx.z;
  int r0 = blockIdx.y * 64, c0 = blockIdx.x * 64;
  const float* ip = in + (size_t)b * ibs;
  unsigned short* op = out + (size_t)b * obs;
  int tid = threadIdx.x;
  int rl = tid >> 4, cl = (tid & 15) * 4;
#pragma unroll
  for (int it = 0; it < 4; ++it) {
    int r = it * 16 + rl;
    float4 v = *(const float4*)(ip + (size_t)(r0 + r) * C + c0 + cl);
    tile[r][cl] = v.x; tile[r][cl + 1] = v.y;
    tile[r][cl + 2] = v.z; tile[r][cl + 3] = v.w;
  }
  __syncthreads();
#pragma unroll
  for (int it = 0; it < 4; ++it) {
    int c = it * 16 + rl;
    ushort4 o;
    o.x = f2bf(tile[cl + 0][c]); o.y = f2bf(tile[cl + 1][c]);
    o.z = f2bf(tile[cl + 2][c]); o.w = f2bf(tile[cl + 3][c]);
    *(ushort4*)(op + (size_t)(c0 + c) * R + r0 + cl) = o;
  }
}

// --- merged QKV weight transpose: z in [0,48) -> {Wq,Wk,Wv}[head] ---
__global__ __launch_bounds__(256) void transpose_qkv_kernel(
    const float* __restrict__ Wq, const float* __restrict__ Wk,
    const float* __restrict__ Wv, unsigned short* __restrict__ out) {
  __shared__ float tile[64][65];
  int z = blockIdx.z;
  int wsel = z >> 4, head = z & 15;
  const float* base = (wsel == 0) ? Wq : (wsel == 1) ? Wk : Wv;
  const float* ip = base + (size_t)head * 65536;   // [1024][64] per head
  unsigned short* op = out + (size_t)z * 65536;    // -> [64][1024]
  int r0 = blockIdx.y * 64;
  int tid = threadIdx.x;
  int rl = tid >> 4, cl = (tid & 15) * 4;
#pragma unroll
  for (int it = 0; it < 4; ++it) {
    int r = it * 16 + rl;
    float4 v = *(const float4*)(ip + (size_t)(r0 + r) * 64 + cl);
    tile[r][cl] = v.x; tile[r][cl + 1] = v.y;
    tile[r][cl + 2] = v.z; tile[r][cl + 3] = v.w;
  }
  __syncthreads();
#pragma unroll
  for (int it = 0; it < 4; ++it) {
    int c = it * 16 + rl;
    ushort4 o;
    o.x = f2bf(tile[cl + 0][c]); o.y = f2bf(tile[cl + 1][c]);
    o.z = f2bf(tile[cl + 2][c]); o.w = f2bf(tile[cl + 3][c]);
    *(ushort4*)(op + (size_t)c * 1024 + r0 + cl) = o;
  }
}

// ---- V [B*S][D] bf16 -> Vt [B*H][64][1024] (per-head transpose) ----
__global__ __launch_bounds__(256) void transpose_v_kernel(
    const unsigned short* __restrict__ V, unsigned short* __restrict__ Vt) {
  __shared__ unsigned short tile[64][68];
  int bh = blockIdx.y;
  int b = bh >> 4, h = bh & 15;
  int t0 = blockIdx.x * 64;
  int tid = threadIdx.x;
  int rl = tid >> 4, cl = (tid & 15) * 4;
  const unsigned short* ip = V + ((size_t)(b * SEQ + t0)) * DMODEL + h * HD;
#pragma unroll
  for (int it = 0; it < 4; ++it) {
    int t = it * 16 + rl;
    ushort4 v = *(const ushort4*)(ip + (size_t)t * DMODEL + cl);
    tile[t][cl] = v.x; tile[t][cl + 1] = v.y;
    tile[t][cl + 2] = v.z; tile[t][cl + 3] = v.w;
  }
  __syncthreads();
  unsigned short* op = Vt + ((size_t)bh * HD) * SEQ + t0;
#pragma unroll
  for (int it = 0; it < 4; ++it) {
    int d = it * 16 + rl;
    ushort4 o;
    o.x = tile[cl + 0][d]; o.y = tile[cl + 1][d];
    o.z = tile[cl + 2][d]; o.w = tile[cl + 3][d];
    *(ushort4*)(op + (size_t)d * SEQ + cl) = o;
  }
}

#define QSCALE 0.18033688f  // 0.125 * log2(e)

// ============ 128x128 dbuf GEMM (r7 — QKV/Wo/FF2) ============
template <int EPI>
__global__ __launch_bounds__(512, 4) void gemmdb_kernel(
    const unsigned short* __restrict__ A, const unsigned short* __restrict__ Bt,
    const float* __restrict__ bias, const float* __restrict__ bias2,
    const float* __restrict__ bias3, const float* __restrict__ resid,
    unsigned short* __restrict__ outb, unsigned short* __restrict__ outb2,
    unsigned short* __restrict__ outb3, float* __restrict__ outf,
    int M, int N, int K, int NX) {
  __shared__ __align__(16) unsigned short As[2 * 128 * 64];  // 32 KB
  __shared__ __align__(16) unsigned short Bs[2 * 128 * 64];  // 32 KB

  const int tid = threadIdx.x;
  const int wid = tid >> 6, lane = tid & 63;
  const int l15 = lane & 15, l4 = lane >> 4;
  const int wm = wid >> 1, wn = wid & 1;

  const int id = (int)blockIdx.x;
  const int xcd = id & 7, j = id >> 3;
  const int w = j >> 6, l = j & 63;
  const int spx = (int)gridDim.x >> 9;
  const int nbx8 = NX >> 3;
  const int g = xcd * spx + w;
  const int by = (g / nbx8) * 8 + (l >> 3);
  const int bx = (g % nbx8) * 8 + (l & 7);

  const size_t KBY = (size_t)K * 2;

  const int rS = tid >> 3;
  const int cS = ((tid & 7) ^ (rS & 7)) << 4;
  const char* gA = (const char*)A + (size_t)(by * 128 + rS) * KBY + cS;
  const char* gB = (const char*)Bt + (size_t)(bx * 128 + rS) * KBY + cS;
  char* sA = (char*)As + tid * 16;
  char* sB = (char*)Bs + tid * 16;

  const int rsw = (l4 ^ (l15 & 7)) << 4;
  const char* aRd0 = (const char*)As + (wm * 32 + l15) * 128 + rsw;
  const char* aRd1 = (const char*)As + (wm * 32 + l15) * 128 + (rsw ^ 64);
  const char* bRd0 = (const char*)Bs + (wn * 64 + l15) * 128 + rsw;
  const char* bRd1 = (const char*)Bs + (wn * 64 + l15) * 128 + (rsw ^ 64);

  f32x4 acc[2][4];
  const f32x4 fz = {0.f, 0.f, 0.f, 0.f};
#pragma unroll
  for (int i = 0; i < 2; ++i)
#pragma unroll
    for (int j2 = 0; j2 < 4; ++j2) acc[i][j2] = fz;

  const int nt = K >> 6;

  gload_lds16(gA, sA);
  gload_lds16(gA + 64 * KBY, sA + 8192);
  gload_lds16(gB, sB);
  gload_lds16(gB + 64 * KBY, sB + 8192);
  asm volatile("s_waitcnt vmcnt(0)" ::: "memory");
  __builtin_amdgcn_sched_barrier(0);
  __builtin_amdgcn_s_barrier();
  __builtin_amdgcn_sched_barrier(0);

#pragma unroll 1
  for (int t = 0; t < nt; ++t) {
    const int cur = t & 1;
    if (t + 1 < nt) {
      const size_t ko = (size_t)(t + 1) << 7;
      const int nb = (cur ^ 1) << 14;
      gload_lds16(gA + ko, sA + nb);
      gload_lds16(gA + 64 * KBY + ko, sA + nb + 8192);
      gload_lds16(gB + ko, sB + nb);
      gload_lds16(gB + 64 * KBY + ko, sB + nb + 8192);
    }
    const int off = cur << 14;
#pragma unroll
    for (int kk = 0; kk < 2; ++kk) {
      const char* aR = (kk ? aRd1 : aRd0) + off;
      const char* bR = (kk ? bRd1 : bRd0) + off;
      bf16x8 afr[2], bfr[4];
#pragma unroll
      for (int ni = 0; ni < 4; ++ni) bfr[ni] = *(const bf16x8*)(bR + ni * 2048);
#pragma unroll
      for (int mi = 0; mi < 2; ++mi) afr[mi] = *(const bf16x8*)(aR + mi * 2048);
      __builtin_amdgcn_s_setprio(1);
#pragma unroll
      for (int mi = 0; mi < 2; ++mi)
#pragma unroll
        for (int ni = 0; ni < 4; ++ni)
          acc[mi][ni] = __builtin_amdgcn_mfma_f32_16x16x32_bf16(
              afr[mi], bfr[ni], acc[mi][ni], 0, 0, 0);
      __builtin_amdgcn_s_setprio(0);
    }
    asm volatile("s_waitcnt vmcnt(0)" ::: "memory");
    __builtin_amdgcn_sched_barrier(0);
    __builtin_amdgcn_s_barrier();
    __builtin_amdgcn_sched_barrier(0);
  }

  if (EPI == 5) {
    const int range = bx >> 3;
    const float* bp = (range == 0) ? bias : (range == 1) ? bias2 : bias3;
    unsigned short* op = (range == 0) ? outb : (range == 1) ? outb2 : outb3;
    const float scale = (range == 0) ? QSCALE : 1.0f;
#pragma unroll
    for (int mi = 0; mi < 2; ++mi) {
#pragma unroll
      for (int ni = 0; ni < 4; ++ni) {
        int colL = (bx & 7) * 128 + wn * 64 + ni * 16 + l15;
        float bn = bp[colL];
#pragma unroll
        for (int jj = 0; jj < 4; ++jj) {
          int row = by * 128 + wm * 32 + mi * 16 + l4 * 4 + jj;
          op[(size_t)row * 1024 + colL] = f2bf((acc[mi][ni][jj] + bn) * scale);
        }
      }
    }
  } else {
#pragma unroll
    for (int mi = 0; mi < 2; ++mi) {
#pragma unroll
      for (int ni = 0; ni < 4; ++ni) {
        int col = bx * 128 + wn * 64 + ni * 16 + l15;
        float bn = bias[col];
#pragma unroll
        for (int jj = 0; jj < 4; ++jj) {
          int row = by * 128 + wm * 32 + mi * 16 + l4 * 4 + jj;
          float v = acc[mi][ni][jj] + bn;
          if (EPI == 1) {
            outf[(size_t)row * N + col] = v + resid[(size_t)row * N + col];
          } else if (EPI == 2) {
            float gel = 0.5f * v * (1.0f + erff(v * 0.70710678118f));
            outb[(size_t)row * N + col] = f2bf(gel);
          } else {
            outb[(size_t)row * N + col] = f2bf(v);
          }
        }
      }
    }
  }
}

// ==== 256x256 / BK=32 dbuf GEMM, wave 128x64, 2 blocks/CU (FF1 only) ====
// 512 thr = 8 waves (2M x 4N), wave tile 128x64 (acc 8x4). BK=32 keeps the
// dbuf at 64KB -> 2 blocks/CU = 2 barrier domains AND reads/MFMA = 12/32
// (LDS pipe 1152 cyc < MFMA 1242 cyc per block-tile). r7 skeleton: stage
// next tile, frag reads + MFMA, own-wave vmcnt(0) drain, one barrier.
// Swizzle: 64B rows, phys16B-chunk = logical ^ ((row>>1)&3) (r9-verified).
__global__ __launch_bounds__(512, 2) void gemmbig2_kernel(
    const unsigned short* __restrict__ A, const unsigned short* __restrict__ Bt,
    const float* __restrict__ bias, unsigned short* __restrict__ outb,
    int M, int N, int K, int YPX) {
  __shared__ __align__(16) unsigned short As[2 * 256 * 32];  // 32 KB
  __shared__ __align__(16) unsigned short Bs[2 * 256 * 32];  // 32 KB

  const int tid = threadIdx.x;
  const int wid = tid >> 6, lane = tid & 63;
  const int l15 = lane & 15, l4 = lane >> 4;
  const int wm = wid >> 2, wn = wid & 3;  // 2 M-waves x 4 N-waves

  // bijective per-XCD panel map
  const int id = (int)blockIdx.x;
  const int xcd = id & 7, i0 = id >> 3;
  const int by = xcd * YPX + (i0 % YPX);
  const int bx = i0 / YPX;

  const size_t KBY = (size_t)K * 2;

  // staging: thread -> row tid>>2 (0..127) and +128; 16B chunk tid&3
  const int rS = tid >> 2;
  const int cS = ((tid & 3) ^ ((rS >> 1) & 3)) << 4;  // invariant under +128
  const char* gA = (const char*)A + (size_t)(by * 256 + rS) * KBY + cS;
  const char* gB = (const char*)Bt + (size_t)(bx * 256 + rS) * KBY + cS;
  char* sA = (char*)As + tid * 16;  // +8192 rows 128..255; +16384 dbuf
  char* sB = (char*)Bs + tid * 16;

  // frag reads: one bf16x8 per row, chunk l4, phys = l4 ^ ((l15>>1)&3)
  const int fsw = (l4 ^ ((l15 >> 1) & 3)) << 4;
  const char* aRd = (const char*)As + (wm * 128 + l15) * 64 + fsw;
  const char* bRd = (const char*)Bs + (wn * 64 + l15) * 64 + fsw;

  f32x4 acc[8][4];
  const f32x4 fz = {0.f, 0.f, 0.f, 0.f};
#pragma unroll
  for (int i = 0; i < 8; ++i)
#pragma unroll
    for (int n = 0; n < 4; ++n) acc[i][n] = fz;

  const int nt = K >> 5;

#define STG2(NB, KO)                                                        \
  do {                                                                      \
    gload_lds16(gA + (KO), sA + (NB));                                      \
    gload_lds16(gA + 128 * KBY + (KO), sA + (NB) + 8192);                   \
    gload_lds16(gB + (KO), sB + (NB));                                      \
    gload_lds16(gB + 128 * KBY + (KO), sB + (NB) + 8192);                   \
  } while (0)

  STG2(0, 0);
  asm volatile("s_waitcnt vmcnt(0)" ::: "memory");
  __builtin_amdgcn_sched_barrier(0);
  __builtin_amdgcn_s_barrier();
  __builtin_amdgcn_sched_barrier(0);

#pragma unroll 1
  for (int t = 0; t < nt; ++t) {
    const int cur = t & 1;
    if (t + 1 < nt) STG2((cur ^ 1) << 14, (size_t)(t + 1) << 6);
    const int off = cur << 14;
    {
      const char* aB = aRd + off;
      const char* bB = bRd + off;
      bf16x8 av[8], bv[4];
#pragma unroll
      for (int ni = 0; ni < 4; ++ni) bv[ni] = *(const bf16x8*)(bB + ni * 1024);
#pragma unroll
      for (int mi = 0; mi < 8; ++mi) av[mi] = *(const bf16x8*)(aB + mi * 1024);
      __builtin_amdgcn_s_setprio(1);
#pragma unroll
      for (int mi = 0; mi < 8; ++mi)
#pragma unroll
        for (int ni = 0; ni < 4; ++ni)
          acc[mi][ni] = __builtin_amdgcn_mfma_f32_16x16x32_bf16(
              av[mi], bv[ni], acc[mi][ni], 0, 0, 0);
      __builtin_amdgcn_s_setprio(0);
    }
    asm volatile("s_waitcnt vmcnt(0)" ::: "memory");
    __builtin_amdgcn_sched_barrier(0);
    __builtin_amdgcn_s_barrier();
    __builtin_amdgcn_sched_barrier(0);
  }

  // epilogue: +bias, exact GELU -> bf16
#pragma unroll
  for (int mi = 0; mi < 8; ++mi) {
#pragma unroll
    for (int ni = 0; ni < 4; ++ni) {
      int col = bx * 256 + wn * 64 + ni * 16 + l15;
      float bn = bias[col];
#pragma unroll
      for (int jj = 0; jj < 4; ++jj) {
        int row = by * 256 + wm * 128 + mi * 16 + l4 * 4 + jj;
        float v = acc[mi][ni][jj] + bn;
        float gel = 0.5f * v * (1.0f + erff(v * 0.70710678118f));
        outb[(size_t)row * N + col] = f2bf(gel);
      }
    }
  }
#undef STG2
}

// ---- Flash attention: swapped QK^T -> in-register P -> K=16 PV (r14) ----
__global__ __launch_bounds__(256, 3) void attn_kernel(
    const unsigned short* __restrict__ Q, const unsigned short* __restrict__ K,
    const unsigned short* __restrict__ Vt, unsigned short* __restrict__ O) {
  __shared__ __align__(16) unsigned short Ks[128 * 64];  // [key][d] swizzled
  __shared__ __align__(16) unsigned short Vs[64 * 128];  // [d][key] swizzled
  int tid = threadIdx.x, wid = tid >> 6, lane = tid & 63;
  int l15 = lane & 15, l4 = lane >> 4;
  int sid = blockIdx.x;
  int aid = (sid & 7) * 256 + (sid >> 3);
  int bh = aid >> 4, qb = aid & 15;
  int b = bh >> 4, h = bh & 15;
  int q0 = qb * 64 + wid * 16;
  const f32x4 fz = {0.f, 0.f, 0.f, 0.f};

  const unsigned short* Qbase = Q + ((size_t)(b * SEQ + q0)) * DMODEL + h * HD;
  bf16x8 qf[2];
#pragma unroll
  for (int kh = 0; kh < 2; ++kh)
    qf[kh] = *(const bf16x8*)(Qbase + (size_t)l15 * DMODEL + kh * 32 + l4 * 8);

  f32x4 o[4];
#pragma unroll
  for (int i = 0; i < 4; ++i) o[i] = fz;
  float mrun = -1e30f, lrun = 0.0f;

  const unsigned short* Kb = K + (size_t)b * SEQ * DMODEL + h * HD;
  const unsigned short* Vb = Vt + (size_t)bh * HD * SEQ;
  int krow = tid >> 3, kchunk = tid & 7;
  int vrow = tid >> 4, vchunk = tid & 15;

  for (int t0 = 0; t0 < SEQ; t0 += 128) {
    __syncthreads();
#pragma unroll
    for (int p = 0; p < 4; ++p) {
      int kr = p * 32 + krow;
      int kg = kchunk ^ (kr & 7);
      gload_lds16(Kb + (size_t)(t0 + kr) * DMODEL + kg * 8,
                  (char*)Ks + p * 4096 + tid * 16);
      int vr = p * 16 + vrow;
      int vg = vchunk ^ (vr & 7);
      gload_lds16(Vb + (size_t)vr * SEQ + t0 + vg * 8,
                  (char*)Vs + p * 4096 + tid * 16);
    }
    __syncthreads();
    f32x4 s[8];
#pragma unroll
    for (int ts = 0; ts < 8; ++ts) {
      int row = ts * 16 + l15;
      bf16x8 k0f = *(const bf16x8*)((const char*)Ks + row * 128 + ((l4) ^ (row & 7)) * 16);
      bf16x8 k1f = *(const bf16x8*)((const char*)Ks + row * 128 + ((4 + l4) ^ (row & 7)) * 16);
      s[ts] = __builtin_amdgcn_mfma_f32_16x16x32_bf16(k0f, qf[0], fz, 0, 0, 0);
      s[ts] = __builtin_amdgcn_mfma_f32_16x16x32_bf16(k1f, qf[1], s[ts], 0, 0, 0);
    }
    float tsm[8];
#pragma unroll
    for (int ts = 0; ts < 8; ++ts)
      tsm[ts] = fmaxf(fmaxf(s[ts][0], s[ts][1]), fmaxf(s[ts][2], s[ts][3]));
    float tm = fmaxf(fmaxf(fmaxf(tsm[0], tsm[1]), fmaxf(tsm[2], tsm[3])),
                     fmaxf(fmaxf(tsm[4], tsm[5]), fmaxf(tsm[6], tsm[7])));
    tm = fmaxf(tm, __shfl_xor(tm, 16, 64));
    tm = fmaxf(tm, __shfl_xor(tm, 32, 64));
    if (!__all(tm - mrun <= 8.0f)) {
      float mnew = fmaxf(mrun, tm);
      float alpha = __builtin_amdgcn_exp2f(mrun - mnew);
      lrun *= alpha;
      float a0 = __shfl(alpha, l4 * 4 + 0, 64);
      float a1 = __shfl(alpha, l4 * 4 + 1, 64);
      float a2 = __shfl(alpha, l4 * 4 + 2, 64);
      float a3 = __shfl(alpha, l4 * 4 + 3, 64);
#pragma unroll
      for (int d = 0; d < 4; ++d) {
        o[d][0] *= a0; o[d][1] *= a1; o[d][2] *= a2; o[d][3] *= a3;
      }
      mrun = mnew;
    }
    unsigned int pk[8][2];
    float ps = 0.0f;
#pragma unroll
    for (int ts = 0; ts < 8; ++ts) {
      float e0 = __builtin_amdgcn_exp2f(s[ts][0] - mrun);
      float e1 = __builtin_amdgcn_exp2f(s[ts][1] - mrun);
      float e2 = __builtin_amdgcn_exp2f(s[ts][2] - mrun);
      float e3 = __builtin_amdgcn_exp2f(s[ts][3] - mrun);
      ps += (e0 + e1) + (e2 + e3);
      pk[ts][0] = cvt_pk_bf16(e0, e1);
      pk[ts][1] = cvt_pk_bf16(e2, e3);
    }
    ps += __shfl_xor(ps, 16, 64);
    ps += __shfl_xor(ps, 32, 64);
    lrun += ps;
#pragma unroll
    for (int ts = 0; ts < 8; ++ts) {
      s16x4 pf = __builtin_bit_cast(s16x4, (u32x2){pk[ts][0], pk[ts][1]});
#pragma unroll
      for (int d = 0; d < 4; ++d) {
        int vr = d * 16 + l15;
        int chunk = 2 * ts + (l4 >> 1);
        int phys = chunk ^ (vr & 7);
        s16x4 vf = *(const s16x4*)((const char*)Vs + vr * 256 + phys * 16 +
                                   (l4 & 1) * 8);
        o[d] = __builtin_amdgcn_mfma_f32_16x16x16bf16_1k(pf, vf, o[d], 0, 0, 0);
      }
    }
  }
  unsigned short* Ob = O + ((size_t)(b * SEQ + q0)) * DMODEL + h * HD;
  float inv = 1.0f / lrun;
  float i0 = __shfl(inv, l4 * 4 + 0, 64);
  float i1 = __shfl(inv, l4 * 4 + 1, 64);
  float i2 = __shfl(inv, l4 * 4 + 2, 64);
  float i3 = __shfl(inv, l4 * 4 + 3, 64);
#pragma unroll
  for (int d = 0; d < 4; ++d) {
    Ob[(size_t)(l4 * 4 + 0) * DMODEL + d * 16 + l15] = f2bf(o[d][0] * i0);
    Ob[(size_t)(l4 * 4 + 1) * DMODEL + d * 16 + l15] = f2bf(o[d][1] * i1);
    Ob[(size_t)(l4 * 4 + 2) * DMODEL + d * 16 + l15] = f2bf(o[d][2] * i2);
    Ob[(size_t)(l4 * 4 + 3) * DMODEL + d * 16 + l15] = f2bf(o[d][3] * i3);
  }
}

extern "C" void kernel_launch(void* const* d_in, const int* in_sizes, int n_in,
                              void* d_out, int out_size, void* d_ws, size_t ws_size,
                              hipStream_t stream) {
  (void)in_sizes; (void)n_in; (void)out_size; (void)ws_size;
  const float* x    = (const float*)d_in[0];
  const float* ln1g = (const float*)d_in[1];
  const float* ln1b = (const float*)d_in[2];
  const float* ln2g = (const float*)d_in[3];
  const float* ln2b = (const float*)d_in[4];
  const float* Wq   = (const float*)d_in[5];
  const float* bq   = (const float*)d_in[6];
  const float* Wk   = (const float*)d_in[7];
  const float* bk   = (const float*)d_in[8];
  const float* Wv   = (const float*)d_in[9];
  const float* bv   = (const float*)d_in[10];
  const float* Wo   = (const float*)d_in[11];
  const float* bo   = (const float*)d_in[12];
  const float* W1   = (const float*)d_in[13];
  const float* b1   = (const float*)d_in[14];
  const float* W2   = (const float*)d_in[15];
  const float* b2   = (const float*)d_in[16];
  float* out = (float*)d_out;

  char* ws = (char*)d_ws;
  const size_t MB = 1u << 20;
  unsigned short* wqT = (unsigned short*)(ws + 0 * MB);   // [3072][1024] qkv
  unsigned short* woT = (unsigned short*)(ws + 6 * MB);
  unsigned short* w1T = (unsigned short*)(ws + 8 * MB);   // [4096][1024]
  unsigned short* w2T = (unsigned short*)(ws + 16 * MB);  // [1024][4096]
  unsigned short* hb  = (unsigned short*)(ws + 24 * MB);  // LN out, bf16
  unsigned short* Qb  = (unsigned short*)(ws + 40 * MB);
  unsigned short* Kb  = (unsigned short*)(ws + 56 * MB);
  unsigned short* Vb  = (unsigned short*)(ws + 72 * MB);
  unsigned short* Vt  = (unsigned short*)(ws + 88 * MB);  // [128][64][1024]
  unsigned short* Ob  = Vb;                                // reuse V after Vt
  unsigned short* ff1 = (unsigned short*)(ws + 40 * MB);  // reuses QKV

  // QKV weights -> bf16 transposed [3072][1024] (one merged launch)
  transpose_qkv_kernel<<<dim3(1, 16, 48), 256, 0, stream>>>(Wq, Wk, Wv, wqT);
  transpose_f2b_kernel<<<dim3(16, 16, 1), 256, 0, stream>>>(Wo, woT, 1024, 1024, 0, 0);
  transpose_f2b_kernel<<<dim3(64, 16, 1), 256, 0, stream>>>(W1, w1T, 1024, 4096, 0, 0);
  transpose_f2b_kernel<<<dim3(16, 64, 1), 256, 0, stream>>>(W2, w2T, 4096, 1024, 0, 0);

  // h = LN1(x)
  ln_bf16_kernel<<<dim3(ROWS), 256, 0, stream>>>(x, ln1g, ln1b, hb);

  // fused QKV projection: N=3072 (Q pre-scaled for exp2 softmax) — r14 config
  gemmdb_kernel<5><<<dim3(1536), 512, 0, stream>>>(
      hb, wqT, bq, bk, bv, nullptr, Qb, Kb, Vb, nullptr, ROWS, 1024, DMODEL, 24);

  // V -> Vt per (b,h)
  transpose_v_kernel<<<dim3(16, 128), 256, 0, stream>>>(Vb, Vt);

  // attention -> O (concat-head layout), XCD-swizzled 1D grid
  attn_kernel<<<dim3(2048), 256, 0, stream>>>(Qb, Kb, Vt, Ob);

  // x2 = x + O @ Wo + bo   (f32, stored in d_out)
  gemmdb_kernel<1><<<dim3(512), 512, 0, stream>>>(
      Ob, woT, bo, nullptr, nullptr, x, nullptr, nullptr, nullptr, out,
      ROWS, DMODEL, DMODEL, 8);

  // h2 = LN2(x2)
  ln_bf16_kernel<<<dim3(ROWS), 256, 0, stream>>>(out, ln2g, ln2b, hb);

  // ff1 = gelu(h2 @ W1 + b1)  — A/B: 256x256/BK=32 wave-128x64, 2 blocks/CU
  // grid 32by x 16bx = 512 blocks, YPX = 4
  gemmbig2_kernel<<<dim3(512), 512, 0, stream>>>(
      hb, w1T, b1, ff1, ROWS, FFDIM, DMODEL, 4);

  // out = x2 + ff1 @ W2 + b2  (control: gemmdb, same FLOP as FF1)
  gemmdb_kernel<1><<<dim3(512), 512, 0, stream>>>(
      ff1, w2T, b2, nullptr, nullptr, out, nullptr, nullptr, nullptr, out,
      ROWS, DMODEL, FFDIM, 8);
}

// Round 17
// 362.765 us; speedup vs baseline: 1.0384x; 1.0384x over previous
//
#include <hip/hip_runtime.h>
#include <hip/hip_bf16.h>
#include <math.h>

#define DMODEL 1024
#define NH     16
#define HD     64
#define FFDIM  4096
#define SEQ    1024
#define BATCH  8
#define ROWS   (BATCH * SEQ)  // 8192

typedef __bf16 bf16x8 __attribute__((ext_vector_type(8)));
typedef __bf16 bf16x4 __attribute__((ext_vector_type(4)));
typedef float  f32x4  __attribute__((ext_vector_type(4)));
typedef short  s16x4  __attribute__((ext_vector_type(4)));
typedef unsigned int u32x2 __attribute__((ext_vector_type(2)));

__device__ __forceinline__ unsigned short f2bf(float f) {
  unsigned int u = __builtin_bit_cast(unsigned int, f);
  u += 0x7fff + ((u >> 16) & 1);
  return (unsigned short)(u >> 16);
}

__device__ __forceinline__ unsigned int cvt_pk_bf16(float lo, float hi) {
  unsigned int r;
  asm("v_cvt_pk_bf16_f32 %0, %1, %2" : "=v"(r) : "v"(lo), "v"(hi));
  return r;
}

__device__ __forceinline__ void gload_lds16(const void* g, void* l) {
  __builtin_amdgcn_global_load_lds(
      (const __attribute__((address_space(1))) unsigned int*)g,
      (__attribute__((address_space(3))) unsigned int*)l, 16, 0, 0);
}

// ---------------- LayerNorm: f32 [rows][1024] -> bf16 ----------------
__global__ __launch_bounds__(256) void ln_bf16_kernel(
    const float* __restrict__ x, const float* __restrict__ g,
    const float* __restrict__ bta, unsigned short* __restrict__ out) {
  int row = blockIdx.x;
  int tid = threadIdx.x;
  int wid = tid >> 6, lane = tid & 63;
  const float4 v = ((const float4*)(x + (size_t)row * DMODEL))[tid];
  float s = v.x + v.y + v.z + v.w;
#pragma unroll
  for (int off = 32; off >= 1; off >>= 1) s += __shfl_xor(s, off, 64);
  __shared__ float red[8];
  if (lane == 0) red[wid] = s;
  __syncthreads();
  float mu = (red[0] + red[1] + red[2] + red[3]) * (1.0f / DMODEL);
  float4 d;
  d.x = v.x - mu; d.y = v.y - mu; d.z = v.z - mu; d.w = v.w - mu;
  float sq = d.x * d.x + d.y * d.y + d.z * d.z + d.w * d.w;
#pragma unroll
  for (int off = 32; off >= 1; off >>= 1) sq += __shfl_xor(sq, off, 64);
  if (lane == 0) red[4 + wid] = sq;
  __syncthreads();
  float var = (red[4] + red[5] + red[6] + red[7]) * (1.0f / DMODEL);
  float rs = rsqrtf(var + 1e-5f);
  const float4 gg = ((const float4*)g)[tid];
  const float4 bb = ((const float4*)bta)[tid];
  ushort4 o;
  o.x = f2bf(d.x * rs * gg.x + bb.x);
  o.y = f2bf(d.y * rs * gg.y + bb.y);
  o.z = f2bf(d.z * rs * gg.z + bb.z);
  o.w = f2bf(d.w * rs * gg.w + bb.w);
  ((ushort4*)(out + (size_t)row * DMODEL))[tid] = o;
}

// ------------- transpose f32 [R][C] -> bf16 [C][R], batched -------------
__global__ __launch_bounds__(256) void transpose_f2b_kernel(
    const float* __restrict__ in, unsigned short* __restrict__ out,
    int R, int C, long long ibs, long long obs) {
  __shared__ float tile[64][65];
  int b = blockIdx.z;
  int r0 = blockIdx.y * 64, c0 = blockIdx.x * 64;
  const float* ip = in + (size_t)b * ibs;
  unsigned short* op = out + (size_t)b * obs;
  int tid = threadIdx.x;
  int rl = tid >> 4, cl = (tid & 15) * 4;
#pragma unroll
  for (int it = 0; it < 4; ++it) {
    int r = it * 16 + rl;
    float4 v = *(const float4*)(ip + (size_t)(r0 + r) * C + c0 + cl);
    tile[r][cl] = v.x; tile[r][cl + 1] = v.y;
    tile[r][cl + 2] = v.z; tile[r][cl + 3] = v.w;
  }
  __syncthreads();
#pragma unroll
  for (int it = 0; it < 4; ++it) {
    int c = it * 16 + rl;
    ushort4 o;
    o.x = f2bf(tile[cl + 0][c]); o.y = f2bf(tile[cl + 1][c]);
    o.z = f2bf(tile[cl + 2][c]); o.w = f2bf(tile[cl + 3][c]);
    *(ushort4*)(op + (size_t)(c0 + c) * R + r0 + cl) = o;
  }
}

// --- merged QKV weight transpose: z in [0,48) -> {Wq,Wk,Wv}[head] ---
__global__ __launch_bounds__(256) void transpose_qkv_kernel(
    const float* __restrict__ Wq, const float* __restrict__ Wk,
    const float* __restrict__ Wv, unsigned short* __restrict__ out) {
  __shared__ float tile[64][65];
  int z = blockIdx.z;
  int wsel = z >> 4, head = z & 15;
  const float* base = (wsel == 0) ? Wq : (wsel == 1) ? Wk : Wv;
  const float* ip = base + (size_t)head * 65536;   // [1024][64] per head
  unsigned short* op = out + (size_t)z * 65536;    // -> [64][1024]
  int r0 = blockIdx.y * 64;
  int tid = threadIdx.x;
  int rl = tid >> 4, cl = (tid & 15) * 4;
#pragma unroll
  for (int it = 0; it < 4; ++it) {
    int r = it * 16 + rl;
    float4 v = *(const float4*)(ip + (size_t)(r0 + r) * 64 + cl);
    tile[r][cl] = v.x; tile[r][cl + 1] = v.y;
    tile[r][cl + 2] = v.z; tile[r][cl + 3] = v.w;
  }
  __syncthreads();
#pragma unroll
  for (int it = 0; it < 4; ++it) {
    int c = it * 16 + rl;
    ushort4 o;
    o.x = f2bf(tile[cl + 0][c]); o.y = f2bf(tile[cl + 1][c]);
    o.z = f2bf(tile[cl + 2][c]); o.w = f2bf(tile[cl + 3][c]);
    *(ushort4*)(op + (size_t)c * 1024 + r0 + cl) = o;
  }
}

// ---- V [B*S][D] bf16 -> Vt [B*H][64][1024] (per-head transpose) ----
__global__ __launch_bounds__(256) void transpose_v_kernel(
    const unsigned short* __restrict__ V, unsigned short* __restrict__ Vt) {
  __shared__ unsigned short tile[64][68];
  int bh = blockIdx.y;
  int b = bh >> 4, h = bh & 15;
  int t0 = blockIdx.x * 64;
  int tid = threadIdx.x;
  int rl = tid >> 4, cl = (tid & 15) * 4;
  const unsigned short* ip = V + ((size_t)(b * SEQ + t0)) * DMODEL + h * HD;
#pragma unroll
  for (int it = 0; it < 4; ++it) {
    int t = it * 16 + rl;
    ushort4 v = *(const ushort4*)(ip + (size_t)t * DMODEL + cl);
    tile[t][cl] = v.x; tile[t][cl + 1] = v.y;
    tile[t][cl + 2] = v.z; tile[t][cl + 3] = v.w;
  }
  __syncthreads();
  unsigned short* op = Vt + ((size_t)bh * HD) * SEQ + t0;
#pragma unroll
  for (int it = 0; it < 4; ++it) {
    int d = it * 16 + rl;
    ushort4 o;
    o.x = tile[cl + 0][d]; o.y = tile[cl + 1][d];
    o.z = tile[cl + 2][d]; o.w = tile[cl + 3][d];
    *(ushort4*)(op + (size_t)d * SEQ + cl) = o;
  }
}

// ============ 128x128 dbuf GEMM: C[M][N] = A[M][K] * Bt[N][K]^T ============
// r7 configuration, verbatim (best measured). 512 threads = 8 waves (4M x 2N),
// wave 32x64, BK=64, dbuf 64KB -> 2 blocks/CU. One barrier + own-wave
// vmcnt(0) drain per K-tile. Superblock L2 map (8by x 8bx / XCD).
#define QSCALE 0.18033688f  // 0.125 * log2(e)

template <int EPI>
__global__ __launch_bounds__(512, 4) void gemmdb_kernel(
    const unsigned short* __restrict__ A, const unsigned short* __restrict__ Bt,
    const float* __restrict__ bias, const float* __restrict__ bias2,
    const float* __restrict__ bias3, const float* __restrict__ resid,
    unsigned short* __restrict__ outb, unsigned short* __restrict__ outb2,
    unsigned short* __restrict__ outb3, float* __restrict__ outf,
    int M, int N, int K, int NX) {
  __shared__ __align__(16) unsigned short As[2 * 128 * 64];  // 32 KB
  __shared__ __align__(16) unsigned short Bs[2 * 128 * 64];  // 32 KB

  const int tid = threadIdx.x;
  const int wid = tid >> 6, lane = tid & 63;
  const int l15 = lane & 15, l4 = lane >> 4;
  const int wm = wid >> 1, wn = wid & 1;

  const int id = (int)blockIdx.x;
  const int xcd = id & 7, j = id >> 3;
  const int w = j >> 6, l = j & 63;
  const int spx = (int)gridDim.x >> 9;
  const int nbx8 = NX >> 3;
  const int g = xcd * spx + w;
  const int by = (g / nbx8) * 8 + (l >> 3);
  const int bx = (g % nbx8) * 8 + (l & 7);

  const size_t KBY = (size_t)K * 2;

  const int rS = tid >> 3;
  const int cS = ((tid & 7) ^ (rS & 7)) << 4;
  const char* gA = (const char*)A + (size_t)(by * 128 + rS) * KBY + cS;
  const char* gB = (const char*)Bt + (size_t)(bx * 128 + rS) * KBY + cS;
  char* sA = (char*)As + tid * 16;
  char* sB = (char*)Bs + tid * 16;

  const int rsw = (l4 ^ (l15 & 7)) << 4;
  const char* aRd0 = (const char*)As + (wm * 32 + l15) * 128 + rsw;
  const char* aRd1 = (const char*)As + (wm * 32 + l15) * 128 + (rsw ^ 64);
  const char* bRd0 = (const char*)Bs + (wn * 64 + l15) * 128 + rsw;
  const char* bRd1 = (const char*)Bs + (wn * 64 + l15) * 128 + (rsw ^ 64);

  f32x4 acc[2][4];
  const f32x4 fz = {0.f, 0.f, 0.f, 0.f};
#pragma unroll
  for (int i = 0; i < 2; ++i)
#pragma unroll
    for (int j2 = 0; j2 < 4; ++j2) acc[i][j2] = fz;

  const int nt = K >> 6;

  gload_lds16(gA, sA);
  gload_lds16(gA + 64 * KBY, sA + 8192);
  gload_lds16(gB, sB);
  gload_lds16(gB + 64 * KBY, sB + 8192);
  asm volatile("s_waitcnt vmcnt(0)" ::: "memory");
  __builtin_amdgcn_sched_barrier(0);
  __builtin_amdgcn_s_barrier();
  __builtin_amdgcn_sched_barrier(0);

#pragma unroll 1
  for (int t = 0; t < nt; ++t) {
    const int cur = t & 1;
    if (t + 1 < nt) {
      const size_t ko = (size_t)(t + 1) << 7;
      const int nb = (cur ^ 1) << 14;
      gload_lds16(gA + ko, sA + nb);
      gload_lds16(gA + 64 * KBY + ko, sA + nb + 8192);
      gload_lds16(gB + ko, sB + nb);
      gload_lds16(gB + 64 * KBY + ko, sB + nb + 8192);
    }
    const int off = cur << 14;
#pragma unroll
    for (int kk = 0; kk < 2; ++kk) {
      const char* aR = (kk ? aRd1 : aRd0) + off;
      const char* bR = (kk ? bRd1 : bRd0) + off;
      bf16x8 afr[2], bfr[4];
#pragma unroll
      for (int ni = 0; ni < 4; ++ni) bfr[ni] = *(const bf16x8*)(bR + ni * 2048);
#pragma unroll
      for (int mi = 0; mi < 2; ++mi) afr[mi] = *(const bf16x8*)(aR + mi * 2048);
      __builtin_amdgcn_s_setprio(1);
#pragma unroll
      for (int mi = 0; mi < 2; ++mi)
#pragma unroll
        for (int ni = 0; ni < 4; ++ni)
          acc[mi][ni] = __builtin_amdgcn_mfma_f32_16x16x32_bf16(
              afr[mi], bfr[ni], acc[mi][ni], 0, 0, 0);
      __builtin_amdgcn_s_setprio(0);
    }
    asm volatile("s_waitcnt vmcnt(0)" ::: "memory");
    __builtin_amdgcn_sched_barrier(0);
    __builtin_amdgcn_s_barrier();
    __builtin_amdgcn_sched_barrier(0);
  }

  if (EPI == 5) {
    const int range = bx >> 3;
    const float* bp = (range == 0) ? bias : (range == 1) ? bias2 : bias3;
    unsigned short* op = (range == 0) ? outb : (range == 1) ? outb2 : outb3;
    const float scale = (range == 0) ? QSCALE : 1.0f;
#pragma unroll
    for (int mi = 0; mi < 2; ++mi) {
#pragma unroll
      for (int ni = 0; ni < 4; ++ni) {
        int colL = (bx & 7) * 128 + wn * 64 + ni * 16 + l15;
        float bn = bp[colL];
#pragma unroll
        for (int jj = 0; jj < 4; ++jj) {
          int row = by * 128 + wm * 32 + mi * 16 + l4 * 4 + jj;
          op[(size_t)row * 1024 + colL] = f2bf((acc[mi][ni][jj] + bn) * scale);
        }
      }
    }
  } else {
#pragma unroll
    for (int mi = 0; mi < 2; ++mi) {
#pragma unroll
      for (int ni = 0; ni < 4; ++ni) {
        int col = bx * 128 + wn * 64 + ni * 16 + l15;
        float bn = bias[col];
#pragma unroll
        for (int jj = 0; jj < 4; ++jj) {
          int row = by * 128 + wm * 32 + mi * 16 + l4 * 4 + jj;
          float v = acc[mi][ni][jj] + bn;
          if (EPI == 1) {
            outf[(size_t)row * N + col] = v + resid[(size_t)row * N + col];
          } else if (EPI == 2) {
            float gel = 0.5f * v * (1.0f + erff(v * 0.70710678118f));
            outb[(size_t)row * N + col] = f2bf(gel);
          } else {
            outb[(size_t)row * N + col] = f2bf(v);
          }
        }
      }
    }
  }
}

// ---- Flash attention: swapped QK^T -> in-register P -> K=16 PV (r14) ----
__global__ __launch_bounds__(256, 3) void attn_kernel(
    const unsigned short* __restrict__ Q, const unsigned short* __restrict__ K,
    const unsigned short* __restrict__ Vt, unsigned short* __restrict__ O) {
  __shared__ __align__(16) unsigned short Ks[128 * 64];  // [key][d] swizzled
  __shared__ __align__(16) unsigned short Vs[64 * 128];  // [d][key] swizzled
  int tid = threadIdx.x, wid = tid >> 6, lane = tid & 63;
  int l15 = lane & 15, l4 = lane >> 4;
  int sid = blockIdx.x;
  int aid = (sid & 7) * 256 + (sid >> 3);
  int bh = aid >> 4, qb = aid & 15;
  int b = bh >> 4, h = bh & 15;
  int q0 = qb * 64 + wid * 16;
  const f32x4 fz = {0.f, 0.f, 0.f, 0.f};

  const unsigned short* Qbase = Q + ((size_t)(b * SEQ + q0)) * DMODEL + h * HD;
  bf16x8 qf[2];
#pragma unroll
  for (int kh = 0; kh < 2; ++kh)
    qf[kh] = *(const bf16x8*)(Qbase + (size_t)l15 * DMODEL + kh * 32 + l4 * 8);

  f32x4 o[4];
#pragma unroll
  for (int i = 0; i < 4; ++i) o[i] = fz;
  float mrun = -1e30f, lrun = 0.0f;  // per-lane state for q = l15

  const unsigned short* Kb = K + (size_t)b * SEQ * DMODEL + h * HD;
  const unsigned short* Vb = Vt + (size_t)bh * HD * SEQ;
  int krow = tid >> 3, kchunk = tid & 7;
  int vrow = tid >> 4, vchunk = tid & 15;

  for (int t0 = 0; t0 < SEQ; t0 += 128) {
    __syncthreads();
#pragma unroll
    for (int p = 0; p < 4; ++p) {
      int kr = p * 32 + krow;
      int kg = kchunk ^ (kr & 7);
      gload_lds16(Kb + (size_t)(t0 + kr) * DMODEL + kg * 8,
                  (char*)Ks + p * 4096 + tid * 16);
      int vr = p * 16 + vrow;
      int vg = vchunk ^ (vr & 7);
      gload_lds16(Vb + (size_t)vr * SEQ + t0 + vg * 8,
                  (char*)Vs + p * 4096 + tid * 16);
    }
    __syncthreads();
    f32x4 s[8];
#pragma unroll
    for (int ts = 0; ts < 8; ++ts) {
      int row = ts * 16 + l15;
      bf16x8 k0f = *(const bf16x8*)((const char*)Ks + row * 128 + ((l4) ^ (row & 7)) * 16);
      bf16x8 k1f = *(const bf16x8*)((const char*)Ks + row * 128 + ((4 + l4) ^ (row & 7)) * 16);
      s[ts] = __builtin_amdgcn_mfma_f32_16x16x32_bf16(k0f, qf[0], fz, 0, 0, 0);
      s[ts] = __builtin_amdgcn_mfma_f32_16x16x32_bf16(k1f, qf[1], s[ts], 0, 0, 0);
    }
    float tsm[8];
#pragma unroll
    for (int ts = 0; ts < 8; ++ts)
      tsm[ts] = fmaxf(fmaxf(s[ts][0], s[ts][1]), fmaxf(s[ts][2], s[ts][3]));
    float tm = fmaxf(fmaxf(fmaxf(tsm[0], tsm[1]), fmaxf(tsm[2], tsm[3])),
                     fmaxf(fmaxf(tsm[4], tsm[5]), fmaxf(tsm[6], tsm[7])));
    tm = fmaxf(tm, __shfl_xor(tm, 16, 64));
    tm = fmaxf(tm, __shfl_xor(tm, 32, 64));
    if (!__all(tm - mrun <= 8.0f)) {
      float mnew = fmaxf(mrun, tm);
      float alpha = __builtin_amdgcn_exp2f(mrun - mnew);
      lrun *= alpha;
      float a0 = __shfl(alpha, l4 * 4 + 0, 64);
      float a1 = __shfl(alpha, l4 * 4 + 1, 64);
      float a2 = __shfl(alpha, l4 * 4 + 2, 64);
      float a3 = __shfl(alpha, l4 * 4 + 3, 64);
#pragma unroll
      for (int d = 0; d < 4; ++d) {
        o[d][0] *= a0; o[d][1] *= a1; o[d][2] *= a2; o[d][3] *= a3;
      }
      mrun = mnew;
    }
    unsigned int pk[8][2];
    float ps = 0.0f;
#pragma unroll
    for (int ts = 0; ts < 8; ++ts) {
      float e0 = __builtin_amdgcn_exp2f(s[ts][0] - mrun);
      float e1 = __builtin_amdgcn_exp2f(s[ts][1] - mrun);
      float e2 = __builtin_amdgcn_exp2f(s[ts][2] - mrun);
      float e3 = __builtin_amdgcn_exp2f(s[ts][3] - mrun);
      ps += (e0 + e1) + (e2 + e3);
      pk[ts][0] = cvt_pk_bf16(e0, e1);
      pk[ts][1] = cvt_pk_bf16(e2, e3);
    }
    ps += __shfl_xor(ps, 16, 64);
    ps += __shfl_xor(ps, 32, 64);
    lrun += ps;
#pragma unroll
    for (int ts = 0; ts < 8; ++ts) {
      s16x4 pf = __builtin_bit_cast(s16x4, (u32x2){pk[ts][0], pk[ts][1]});
#pragma unroll
      for (int d = 0; d < 4; ++d) {
        int vr = d * 16 + l15;
        int chunk = 2 * ts + (l4 >> 1);
        int phys = chunk ^ (vr & 7);
        s16x4 vf = *(const s16x4*)((const char*)Vs + vr * 256 + phys * 16 +
                                   (l4 & 1) * 8);
        o[d] = __builtin_amdgcn_mfma_f32_16x16x16bf16_1k(pf, vf, o[d], 0, 0, 0);
      }
    }
  }
  unsigned short* Ob = O + ((size_t)(b * SEQ + q0)) * DMODEL + h * HD;
  float inv = 1.0f / lrun;
  float i0 = __shfl(inv, l4 * 4 + 0, 64);
  float i1 = __shfl(inv, l4 * 4 + 1, 64);
  float i2 = __shfl(inv, l4 * 4 + 2, 64);
  float i3 = __shfl(inv, l4 * 4 + 3, 64);
#pragma unroll
  for (int d = 0; d < 4; ++d) {
    Ob[(size_t)(l4 * 4 + 0) * DMODEL + d * 16 + l15] = f2bf(o[d][0] * i0);
    Ob[(size_t)(l4 * 4 + 1) * DMODEL + d * 16 + l15] = f2bf(o[d][1] * i1);
    Ob[(size_t)(l4 * 4 + 2) * DMODEL + d * 16 + l15] = f2bf(o[d][2] * i2);
    Ob[(size_t)(l4 * 4 + 3) * DMODEL + d * 16 + l15] = f2bf(o[d][3] * i3);
  }
}

extern "C" void kernel_launch(void* const* d_in, const int* in_sizes, int n_in,
                              void* d_out, int out_size, void* d_ws, size_t ws_size,
                              hipStream_t stream) {
  (void)in_sizes; (void)n_in; (void)out_size; (void)ws_size;
  const float* x    = (const float*)d_in[0];
  const float* ln1g = (const float*)d_in[1];
  const float* ln1b = (const float*)d_in[2];
  const float* ln2g = (const float*)d_in[3];
  const float* ln2b = (const float*)d_in[4];
  const float* Wq   = (const float*)d_in[5];
  const float* bq   = (const float*)d_in[6];
  const float* Wk   = (const float*)d_in[7];
  const float* bk   = (const float*)d_in[8];
  const float* Wv   = (const float*)d_in[9];
  const float* bv   = (const float*)d_in[10];
  const float* Wo   = (const float*)d_in[11];
  const float* bo   = (const float*)d_in[12];
  const float* W1   = (const float*)d_in[13];
  const float* b1   = (const float*)d_in[14];
  const float* W2   = (const float*)d_in[15];
  const float* b2   = (const float*)d_in[16];
  float* out = (float*)d_out;

  char* ws = (char*)d_ws;
  const size_t MB = 1u << 20;
  unsigned short* wqT = (unsigned short*)(ws + 0 * MB);   // [3072][1024] qkv
  unsigned short* woT = (unsigned short*)(ws + 6 * MB);
  unsigned short* w1T = (unsigned short*)(ws + 8 * MB);   // [4096][1024]
  unsigned short* w2T = (unsigned short*)(ws + 16 * MB);  // [1024][4096]
  unsigned short* hb  = (unsigned short*)(ws + 24 * MB);  // LN out, bf16
  unsigned short* Qb  = (unsigned short*)(ws + 40 * MB);
  unsigned short* Kb  = (unsigned short*)(ws + 56 * MB);
  unsigned short* Vb  = (unsigned short*)(ws + 72 * MB);
  unsigned short* Vt  = (unsigned short*)(ws + 88 * MB);  // [128][64][1024]
  unsigned short* Ob  = Vb;                                // reuse V after Vt
  unsigned short* ff1 = (unsigned short*)(ws + 40 * MB);  // reuses QKV

  // QKV weights -> bf16 transposed [3072][1024] (one merged launch)
  transpose_qkv_kernel<<<dim3(1, 16, 48), 256, 0, stream>>>(Wq, Wk, Wv, wqT);
  transpose_f2b_kernel<<<dim3(16, 16, 1), 256, 0, stream>>>(Wo, woT, 1024, 1024, 0, 0);
  transpose_f2b_kernel<<<dim3(64, 16, 1), 256, 0, stream>>>(W1, w1T, 1024, 4096, 0, 0);
  transpose_f2b_kernel<<<dim3(16, 64, 1), 256, 0, stream>>>(W2, w2T, 4096, 1024, 0, 0);

  // h = LN1(x)
  ln_bf16_kernel<<<dim3(ROWS), 256, 0, stream>>>(x, ln1g, ln1b, hb);

  // fused QKV projection: N=3072 (Q pre-scaled for exp2 softmax)
  gemmdb_kernel<5><<<dim3(1536), 512, 0, stream>>>(
      hb, wqT, bq, bk, bv, nullptr, Qb, Kb, Vb, nullptr, ROWS, 1024, DMODEL, 24);

  // V -> Vt per (b,h)
  transpose_v_kernel<<<dim3(16, 128), 256, 0, stream>>>(Vb, Vt);

  // attention -> O (concat-head layout), XCD-swizzled 1D grid
  attn_kernel<<<dim3(2048), 256, 0, stream>>>(Qb, Kb, Vt, Ob);

  // x2 = x + O @ Wo + bo   (f32, stored in d_out)
  gemmdb_kernel<1><<<dim3(512), 512, 0, stream>>>(
      Ob, woT, bo, nullptr, nullptr, x, nullptr, nullptr, nullptr, out,
      ROWS, DMODEL, DMODEL, 8);

  // h2 = LN2(x2)
  ln_bf16_kernel<<<dim3(ROWS), 256, 0, stream>>>(out, ln2g, ln2b, hb);

  // ff1 = gelu(h2 @ W1 + b1)
  gemmdb_kernel<2><<<dim3(2048), 512, 0, stream>>>(
      hb, w1T, b1, nullptr, nullptr, nullptr, ff1, nullptr, nullptr, nullptr,
      ROWS, FFDIM, DMODEL, 32);

  // out = x2 + ff1 @ W2 + b2
  gemmdb_kernel<1><<<dim3(512), 512, 0, stream>>>(
      ff1, w2T, b2, nullptr, nullptr, out, nullptr, nullptr, nullptr, out,
      ROWS, DMODEL, FFDIM, 8);
}